// Round 17
// baseline (208.697 us; speedup 1.0000x reference)
//
#include <hip/hip_runtime.h>
#include <hip/hip_bf16.h>

#define NN 100000
#define NE 1600000
#define NF 256
#define NC 40
#define NH 8
#define D1 64
#define NEG 0.2f
#define BSHIFT 7
#define BSZ 128
#define NB ((NN + BSZ - 1) / BSZ)     // 782 buckets of 128 nodes
#define EPB 4096
#define NBLK ((NE + EPB - 1) / EPB)   // 391 edge blocks

typedef __attribute__((ext_vector_type(8))) short short8;
typedef __attribute__((ext_vector_type(4))) float f32x4;

static __device__ __forceinline__ float lrelu(float x) { return x > 0.f ? x : NEG * x; }

static __device__ __forceinline__ float2 bfx2(unsigned u) {
    union { unsigned q; float f; } a, b;
    a.q = u << 16;
    b.q = u & 0xFFFF0000u;
    return make_float2(a.f, b.f);
}

static __device__ __forceinline__ unsigned packbf2(float x, float y) {
    unsigned xu = __float_as_uint(x), yu = __float_as_uint(y);
    xu = (xu + 0x7FFFu + ((xu >> 16) & 1u)) >> 16;
    yu = (yu + 0x7FFFu + ((yu >> 16) & 1u)) >> 16;
    return xu | (yu << 16);
}

static __device__ __forceinline__ unsigned short f2b(float x) {
    unsigned u = __float_as_uint(x);
    u = (u + 0x7FFFu + ((u >> 16) & 1u)) >> 16;
    return (unsigned short)u;
}

// src quartile (0..3) -- 25000-node windows (~3.2MB of h1b each, fits 4MB L2)
static __device__ __forceinline__ int quart(int s) {
    return (s >= 50000) ? (s >= 75000 ? 3 : 2) : (s >= 25000 ? 1 : 0);
}

// ---------------- CSR build: deterministic multi-split, 4-byte records ----------------

__launch_bounds__(256)
__global__ void bhist_k(const int* __restrict__ dst, int* __restrict__ cnt) {
    __shared__ int hist[NB];
    int i = blockIdx.x, t = threadIdx.x;
    for (int b = t; b < NB; b += 256) hist[b] = 0;
    __syncthreads();
    int e0 = i * EPB;
    #pragma unroll
    for (int k = 0; k < EPB / 256; ++k) {
        int e = e0 + k * 256 + t;
        if (e < NE) atomicAdd(&hist[dst[e] >> BSHIFT], 1);
    }
    __syncthreads();
    for (int b = t; b < NB; b += 256) cnt[i * NB + b] = hist[b];
}

__launch_bounds__(256)
__global__ void bscan2_k(int* __restrict__ cnt, int* __restrict__ btot) {
    __shared__ int ps[256];
    int b = blockIdx.x, t = threadIdx.x;
    int i0 = 2 * t;
    int a = (i0 < NBLK) ? cnt[i0 * NB + b] : 0;
    int c = (i0 + 1 < NBLK) ? cnt[(i0 + 1) * NB + b] : 0;
    int s = a + c;
    ps[t] = s;
    __syncthreads();
    #pragma unroll
    for (int off = 1; off < 256; off <<= 1) {
        int x = (t >= off) ? ps[t - off] : 0;
        __syncthreads();
        ps[t] += x;
        __syncthreads();
    }
    int ex = ps[t] - s;
    if (i0 < NBLK) cnt[i0 * NB + b] = ex;
    if (i0 + 1 < NBLK) cnt[(i0 + 1) * NB + b] = ex + a;
    if (t == 255) btot[b] = ps[255];
}

__launch_bounds__(256)
__global__ void bscanB_k(const int* __restrict__ btot, int* __restrict__ bbase) {
    __shared__ int ps[256];
    int t = threadIdx.x;
    int j0 = 4 * t;
    int v[4]; int s = 0;
    #pragma unroll
    for (int k = 0; k < 4; ++k) { v[k] = (j0 + k < NB) ? btot[j0 + k] : 0; s += v[k]; }
    ps[t] = s;
    __syncthreads();
    #pragma unroll
    for (int off = 1; off < 256; off <<= 1) {
        int x = (t >= off) ? ps[t - off] : 0;
        __syncthreads();
        ps[t] += x;
        __syncthreads();
    }
    int run = ps[t] - s;
    #pragma unroll
    for (int k = 0; k < 4; ++k) { if (j0 + k < NB) bbase[j0 + k] = run; run += v[k]; }
    if (t == 0) bbase[NB] = NE;
}

// place 4-byte records: (d&127)<<17 | src   (src < 2^17)
__launch_bounds__(256)
__global__ void bplace_k(const int* __restrict__ src, const int* __restrict__ dst,
                         const int* __restrict__ cnt, const int* __restrict__ bbase,
                         unsigned* __restrict__ tmp) {
    __shared__ int loff[NB];
    int i = blockIdx.x, t = threadIdx.x;
    for (int b = t; b < NB; b += 256) loff[b] = bbase[b] + cnt[i * NB + b];
    __syncthreads();
    int e0 = i * EPB;
    #pragma unroll
    for (int k = 0; k < EPB / 256; ++k) {
        int e = e0 + k * 256 + t;
        if (e < NE) {
            int d = dst[e];
            int p = atomicAdd(&loff[d >> BSHIFT], 1);
            tmp[p] = ((unsigned)(d & 127) << 17) | (unsigned)src[e];
        }
    }
}

// final CSR: per-node counts (split by src quartile) -> rowptr; col placed in
// (node, src-quartile) order so agg gathers sweep ~3.2MB windows (L2 locality).
__launch_bounds__(256)
__global__ void scatter2_k(const unsigned* __restrict__ tmp, const int* __restrict__ bbase,
                           int* __restrict__ rowptr, int* __restrict__ col) {
    __shared__ int lcnt[BSZ * 4];   // per (node, quartile) counts -> intra offsets
    __shared__ int lrow[BSZ];
    __shared__ int ls[BSZ];
    int b = blockIdx.x, t = threadIdx.x;
    int n0 = b << BSHIFT;
    for (int idx = t; idx < BSZ * 4; idx += 256) lcnt[idx] = 0;
    __syncthreads();
    int beg = bbase[b], end = bbase[b + 1];
    for (int p = beg + t; p < end; p += 256) {
        unsigned v = tmp[p];
        int dloc = v >> 17;
        int s = (int)(v & 0x1FFFFu);
        atomicAdd(&lcnt[dloc * 4 + quart(s)], 1);
    }
    __syncthreads();
    int c0 = 0, c1 = 0, c2 = 0, c3 = 0, tot = 0;
    if (t < BSZ) {
        c0 = lcnt[t * 4]; c1 = lcnt[t * 4 + 1]; c2 = lcnt[t * 4 + 2]; c3 = lcnt[t * 4 + 3];
        tot = c0 + c1 + c2 + c3;
        ls[t] = tot;
    }
    __syncthreads();
    #pragma unroll
    for (int off = 1; off < BSZ; off <<= 1) {
        int x = 0;
        if (t < BSZ && t >= off) x = ls[t - off];
        __syncthreads();
        if (t < BSZ) ls[t] += x;
        __syncthreads();
    }
    if (t < BSZ) {
        int ex = ls[t] - tot;
        lrow[t] = beg + ex;
        if (n0 + t < NN) rowptr[n0 + t] = beg + ex;
        // intra-node exclusive offsets per quartile (placement counters)
        lcnt[t * 4] = 0;
        lcnt[t * 4 + 1] = c0;
        lcnt[t * 4 + 2] = c0 + c1;
        lcnt[t * 4 + 3] = c0 + c1 + c2;
    }
    if (b == NB - 1 && t == 0) rowptr[NN] = NE;
    __syncthreads();
    for (int p = beg + t; p < end; p += 256) {
        unsigned v = tmp[p];
        int dloc = v >> 17;
        int s = (int)(v & 0x1FFFFu);
        int o = atomicAdd(&lcnt[dloc * 4 + quart(s)], 1);
        col[lrow[dloc] + o] = s;
    }
}

// ---------------- GEMM1 (MFMA): h1 = x @ W1 -> bf16, + fused ad1 epilogue ----------------

__launch_bounds__(256)
__global__ void gemm1_k(const float* __restrict__ x, const float* __restrict__ W,
                        const float* __restrict__ adst1,
                        unsigned short* __restrict__ h1b, float* __restrict__ ad1) {
    __shared__ unsigned short wsw[8 * 4 * 64 * 8];   // 16384 bf16 = 32 KB
    int tid = threadIdx.x;
    int wid = tid >> 6, lane = tid & 63;
    int r0 = blockIdx.x * 128 + wid * 32;

    #pragma unroll
    for (int it = 0; it < 16; ++it) {
        int idx4 = it * 256 + tid;
        int k = idx4 >> 4;
        int c0 = (idx4 & 15) * 4;
        float4 v = *(const float4*)&W[k * 64 + c0];
        int kt = k >> 5, kg = (k >> 3) & 3, kr = k & 7;
        float vv[4] = {v.x, v.y, v.z, v.w};
        #pragma unroll
        for (int j = 0; j < 4; ++j) {
            int c = c0 + j;
            int dest = (((kt * 4 + (c >> 4)) * 64) + kg * 16 + (c & 15)) * 8 + kr;
            wsw[dest] = f2b(vv[j]);
        }
    }
    __syncthreads();

    int arow0 = r0 + (lane & 15);
    int kg8 = (lane >> 4) * 8;
    f32x4 acc[2][4] = {};
    for (int kt = 0; kt < 8; ++kt) {
        short8 af[2];
        #pragma unroll
        for (int rt = 0; rt < 2; ++rt) {
            int row = arow0 + rt * 16;
            float4 v0 = make_float4(0.f, 0.f, 0.f, 0.f), v1 = v0;
            if (row < NN) {
                const float* px = &x[row * NF + kt * 32 + kg8];
                v0 = *(const float4*)px;
                v1 = *(const float4*)(px + 4);
            }
            unsigned p0 = packbf2(v0.x, v0.y), p1 = packbf2(v0.z, v0.w);
            unsigned p2 = packbf2(v1.x, v1.y), p3 = packbf2(v1.z, v1.w);
            af[rt][0] = (short)(p0 & 0xFFFF); af[rt][1] = (short)(p0 >> 16);
            af[rt][2] = (short)(p1 & 0xFFFF); af[rt][3] = (short)(p1 >> 16);
            af[rt][4] = (short)(p2 & 0xFFFF); af[rt][5] = (short)(p2 >> 16);
            af[rt][6] = (short)(p3 & 0xFFFF); af[rt][7] = (short)(p3 >> 16);
        }
        #pragma unroll
        for (int ct = 0; ct < 4; ++ct) {
            short8 bf = *(const short8*)&wsw[((kt * 4 + ct) * 64 + lane) * 8];
            acc[0][ct] = __builtin_amdgcn_mfma_f32_16x16x32_bf16(af[0], bf, acc[0][ct], 0, 0, 0);
            acc[1][ct] = __builtin_amdgcn_mfma_f32_16x16x32_bf16(af[1], bf, acc[1][ct], 0, 0, 0);
        }
    }

    int ccol = lane & 15;
    int crow0 = r0 + (lane >> 4) * 4;
    float adc[4];
    #pragma unroll
    for (int ct = 0; ct < 4; ++ct) adc[ct] = adst1[ct * 16 + ccol];
    int hbase = ccol >> 3;   // 0 or 1

    #pragma unroll
    for (int rt = 0; rt < 2; ++rt) {
        #pragma unroll
        for (int r = 0; r < 4; ++r) {
            int grow = crow0 + rt * 16 + r;
            if (grow < NN) {
                #pragma unroll
                for (int ct = 0; ct < 4; ++ct)
                    h1b[grow * D1 + ct * 16 + ccol] = f2b(acc[rt][ct][r]);
            }
            float pd[4];
            #pragma unroll
            for (int ct = 0; ct < 4; ++ct) pd[ct] = acc[rt][ct][r] * adc[ct];
            #pragma unroll
            for (int off = 1; off <= 4; off <<= 1)
                #pragma unroll
                for (int ct = 0; ct < 4; ++ct) pd[ct] += __shfl_xor(pd[ct], off, 64);
            if ((lane & 7) == 0 && grow < NN) {
                #pragma unroll
                for (int ct = 0; ct < 4; ++ct)
                    ad1[grow * 8 + ct * 2 + hbase] = pd[ct];
            }
        }
    }
}

// ---------------- w2vec precompute: [W2@asrc2 ; W2@adst2] (128 floats) ----------------

__launch_bounds__(128)
__global__ void w2pre_k(const float* __restrict__ W2, const float* __restrict__ asrc,
                        const float* __restrict__ adst, float* __restrict__ w2vec) {
    int t = threadIdx.x;
    int c = t & 63;
    const float* av = (t < 64) ? asrc : adst;
    float s = 0.f;
    #pragma unroll
    for (int j = 0; j < NC; ++j) s = fmaf(W2[c * NC + j], av[j], s);
    w2vec[t] = s;
}

// ---------------- aggregation layer 1: inline as1 recompute + fused attn2 epilogue ----------------

__launch_bounds__(256)
__global__ void agg1_k(const unsigned short* __restrict__ h1b, const float* __restrict__ asrc1,
                       const float* __restrict__ ad1,
                       const int* __restrict__ rowptr, const int* __restrict__ col,
                       const float* __restrict__ b1, const float* __restrict__ w2vec,
                       unsigned short* __restrict__ h1outb,
                       float* __restrict__ as2, float* __restrict__ ad2) {
    int n = blockIdx.x * 4 + (threadIdx.x >> 6);
    if (n >= NN) return;
    int lane = threadIdx.x & 63;
    int g = lane >> 3, ln = lane & 7;
    int row0 = rowptr[n];
    int d = rowptr[n + 1] - row0;
    float adh = ad1[n * 8 + ln];
    float a1c[8];
    #pragma unroll
    for (int k = 0; k < 8; ++k) a1c[k] = asrc1[ln * 8 + k];

    float acc[8] = {};
    float wsum = 0.f;
    for (int j = 0; j <= d; j += 8) {
        int jj = j + g;
        int s = (jj < d) ? col[row0 + jj] : n;   // virtual self-loop at jj==d
        uint4 hv = *(const uint4*)&h1b[s * D1 + ln * 8];
        float f[8];
        float2 p;
        p = bfx2(hv.x); f[0] = p.x; f[1] = p.y;
        p = bfx2(hv.y); f[2] = p.x; f[3] = p.y;
        p = bfx2(hv.z); f[4] = p.x; f[5] = p.y;
        p = bfx2(hv.w); f[6] = p.x; f[7] = p.y;
        float sa = 0.f;
        #pragma unroll
        for (int k = 0; k < 8; ++k) sa = fmaf(f[k], a1c[k], sa);   // as1 recomputed inline
        float wgt = (jj <= d) ? __expf(lrelu(sa + adh)) : 0.f;
        wsum += wgt;
        #pragma unroll
        for (int k = 0; k < 8; ++k) acc[k] = fmaf(f[k], wgt, acc[k]);
    }
    #pragma unroll
    for (int off = 8; off <= 32; off <<= 1) {
        wsum += __shfl_xor(wsum, off, 64);
        #pragma unroll
        for (int k = 0; k < 8; ++k) acc[k] += __shfl_xor(acc[k], off, 64);
    }
    if (g == 0) {
        float inv = 1.f / (wsum + 1e-16f);
        float vals[8];
        #pragma unroll
        for (int k = 0; k < 8; ++k) {
            float v = fmaf(acc[k], inv, b1[ln * 8 + k]);
            vals[k] = (v > 0.f) ? v : (__expf(v) - 1.f);   // ELU
        }
        unsigned u[4];
        #pragma unroll
        for (int k = 0; k < 4; ++k) u[k] = packbf2(vals[2 * k], vals[2 * k + 1]);
        uint4 w = {u[0], u[1], u[2], u[3]};
        *(uint4*)&h1outb[n * D1 + ln * 8] = w;
        float pa = 0.f, pd = 0.f;
        #pragma unroll
        for (int k = 0; k < 8; ++k) {
            pa = fmaf(vals[k], w2vec[ln * 8 + k], pa);
            pd = fmaf(vals[k], w2vec[64 + ln * 8 + k], pd);
        }
        pa += __shfl_xor(pa, 1); pa += __shfl_xor(pa, 2); pa += __shfl_xor(pa, 4);
        pd += __shfl_xor(pd, 1); pd += __shfl_xor(pd, 2); pd += __shfl_xor(pd, 4);
        if (ln == 0) { as2[n] = pa; ad2[n] = pd; }
    }
}

// ---------------- aggregation layer 2 -> zb ----------------

__launch_bounds__(256)
__global__ void agg2_k(const unsigned short* __restrict__ h1outb, const float* __restrict__ as2,
                       const float* __restrict__ ad2,
                       const int* __restrict__ rowptr, const int* __restrict__ col,
                       unsigned short* __restrict__ zb) {
    int n = blockIdx.x * 4 + (threadIdx.x >> 6);
    if (n >= NN) return;
    int lane = threadIdx.x & 63;
    int g = lane >> 3, ln = lane & 7;
    int row0 = rowptr[n];
    int d = rowptr[n + 1] - row0;
    float adn = ad2[n];

    float acc[8] = {};
    float wsum = 0.f;
    for (int j = 0; j <= d; j += 8) {
        int jj = j + g;
        int s = (jj < d) ? col[row0 + jj] : n;
        float e = lrelu(as2[s] + adn);
        float wgt = (jj <= d) ? __expf(e) : 0.f;
        wsum += wgt;
        uint4 hv = *(const uint4*)&h1outb[s * D1 + ln * 8];
        float2 p;
        p = bfx2(hv.x); acc[0] = fmaf(p.x, wgt, acc[0]); acc[1] = fmaf(p.y, wgt, acc[1]);
        p = bfx2(hv.y); acc[2] = fmaf(p.x, wgt, acc[2]); acc[3] = fmaf(p.y, wgt, acc[3]);
        p = bfx2(hv.z); acc[4] = fmaf(p.x, wgt, acc[4]); acc[5] = fmaf(p.y, wgt, acc[5]);
        p = bfx2(hv.w); acc[6] = fmaf(p.x, wgt, acc[6]); acc[7] = fmaf(p.y, wgt, acc[7]);
    }
    #pragma unroll
    for (int off = 8; off <= 32; off <<= 1) {
        wsum += __shfl_xor(wsum, off, 64);
        #pragma unroll
        for (int k = 0; k < 8; ++k) acc[k] += __shfl_xor(acc[k], off, 64);
    }
    if (g == 0) {
        float inv = 1.f / (wsum + 1e-16f);
        unsigned u[4];
        #pragma unroll
        for (int k = 0; k < 4; ++k)
            u[k] = packbf2(acc[2 * k] * inv, acc[2 * k + 1] * inv);
        uint4 w = {u[0], u[1], u[2], u[3]};
        *(uint4*)&zb[n * D1 + ln * 8] = w;
    }
}

// ---------------- GEMM2: out = z @ W2 + b2   [100000,64]x[64,40] -> d_out ----------------

__launch_bounds__(256)
__global__ void gemm2_k(const unsigned short* __restrict__ zb, const float* __restrict__ W2,
                        const float* __restrict__ b2, float* __restrict__ out) {
    __shared__ float xs[64 * 68];
    __shared__ float wsm[64 * 40];
    __shared__ float bs[40];
    int r0 = blockIdx.x * 64;
    int tid = threadIdx.x;
    #pragma unroll
    for (int it = 0; it < 4; ++it) {
        int idx = tid + it * 256;       // 0..1023
        int row = idx >> 4;             // 0..63
        int q = (idx & 15) * 4;         // col quad base
        int gr = r0 + row;
        float f0 = 0.f, f1 = 0.f, f2 = 0.f, f3 = 0.f;
        if (gr < NN) {
            uint2 v = *(const uint2*)&zb[gr * D1 + q];
            float2 p0 = bfx2(v.x), p1 = bfx2(v.y);
            f0 = p0.x; f1 = p0.y; f2 = p1.x; f3 = p1.y;
        }
        xs[row * 68 + q] = f0;
        xs[row * 68 + q + 1] = f1;
        xs[row * 68 + q + 2] = f2;
        xs[row * 68 + q + 3] = f3;
    }
    #pragma unroll
    for (int it = 0; it < 10; ++it) {
        int idx = tid + it * 256;
        if (idx < 64 * 40) wsm[idx] = W2[idx];
    }
    if (tid < 40) bs[tid] = b2[tid];
    __syncthreads();
    int r = tid >> 2, q = tid & 3;
    float acc[10] = {};
    #pragma unroll 4
    for (int k = 0; k < 64; ++k) {
        float xv = xs[r * 68 + k];
        #pragma unroll
        for (int i = 0; i < 10; ++i)
            acc[i] = fmaf(xv, wsm[k * 40 + q * 10 + i], acc[i]);
    }
    int gr = r0 + r;
    if (gr < NN) {
        #pragma unroll
        for (int i = 0; i < 10; ++i) out[gr * NC + q * 10 + i] = acc[i] + bs[q * 10 + i];
    }
}

// ---------------- launcher ----------------

extern "C" void kernel_launch(void* const* d_in, const int* in_sizes, int n_in,
                              void* d_out, int out_size, void* d_ws, size_t ws_size,
                              hipStream_t stream) {
    const float* x = (const float*)d_in[0];
    const int* ei = (const int*)d_in[1];   // harness passes integer inputs as int32
    const int* src = ei;
    const int* dst = ei + NE;
    const float* W1 = (const float*)d_in[2];
    const float* asrc1 = (const float*)d_in[3];
    const float* adst1 = (const float*)d_in[4];
    const float* b1 = (const float*)d_in[5];
    const float* W2 = (const float*)d_in[6];
    const float* asrc2 = (const float*)d_in[7];
    const float* adst2 = (const float*)d_in[8];
    const float* b2 = (const float*)d_in[9];
    float* out = (float*)d_out;

    // workspace layout (total 46,006,912 B):
    //   [0,12800000)          h1b bf16 [N][64]; zb bf16 [N][64] aliases (h1b dead after agg1)
    //   [16000000,19200000)   ad1 fp32 [N][8]
    //   [25600000,38400000)   h1outb bf16 [N][64]; tmp u32 [NE] aliases (dead before agg1)
    //   [38400000,38800000)   as2 fp32 [N]
    //   [38800000,39200000)   ad2 fp32 [N]
    //   [39200000,45600000)   col int [NE]; cnt int [NBLK*NB] aliases (dead before scatter2)
    //   [45600000,46000128)   rowptr int [N+1, padded]
    //   [46000128,46003260)   btot int [NB]
    //   [46003264,46006400)   bbase int [NB+1, padded]
    //   [46006400,46006912)   w2vec fp32 [128]
    char* ws = (char*)d_ws;
    unsigned short* h1b    = (unsigned short*)(ws + 0);
    unsigned short* zb     = (unsigned short*)(ws + 0);      // alias: h1b dead after agg1
    float*          ad1    = (float*)(ws + 16000000);
    unsigned short* h1outb = (unsigned short*)(ws + 25600000);
    unsigned*       tmp    = (unsigned*)(ws + 25600000);     // alias: dead before agg1 writes h1outb
    float*          as2    = (float*)(ws + 38400000);
    float*          ad2    = (float*)(ws + 38800000);
    int*            col    = (int*)(ws + 39200000);
    int*            cnt    = (int*)(ws + 39200000);          // alias: dead before scatter2 writes col
    int*            rowptr = (int*)(ws + 45600000);
    int*            btot   = (int*)(ws + 46000128);
    int*            bbase  = (int*)(ws + 46003264);
    float*          w2vec  = (float*)(ws + 46006400);

    bhist_k<<<NBLK, 256, 0, stream>>>(dst, cnt);
    bscan2_k<<<NB, 256, 0, stream>>>(cnt, btot);
    bscanB_k<<<1, 256, 0, stream>>>(btot, bbase);
    bplace_k<<<NBLK, 256, 0, stream>>>(src, dst, cnt, bbase, tmp);
    scatter2_k<<<NB, 256, 0, stream>>>(tmp, bbase, rowptr, col);

    gemm1_k<<<(NN + 127) / 128, 256, 0, stream>>>(x, W1, adst1, h1b, ad1);
    w2pre_k<<<1, 128, 0, stream>>>(W2, asrc2, adst2, w2vec);
    agg1_k<<<(NN + 3) / 4, 256, 0, stream>>>(h1b, asrc1, ad1, rowptr, col, b1, w2vec,
                                             h1outb, as2, ad2);

    agg2_k<<<(NN + 3) / 4, 256, 0, stream>>>(h1outb, as2, ad2, rowptr, col, zb);
    gemm2_k<<<(NN + 63) / 64, 256, 0, stream>>>(zb, W2, b2, out);
}

// Round 19
// 189.584 us; speedup vs baseline: 1.1008x; 1.1008x over previous
//
#include <hip/hip_runtime.h>
#include <hip/hip_bf16.h>

#define NN 100000
#define NE 1600000
#define NF 256
#define NC 40
#define NH 8
#define D1 64
#define NEG 0.2f
#define BSHIFT 7
#define BSZ 128
#define NB ((NN + BSZ - 1) / BSZ)     // 782 buckets of 128 nodes
#define EPB 4096
#define NBLK ((NE + EPB - 1) / EPB)   // 391 edge blocks

typedef __attribute__((ext_vector_type(8))) short short8;
typedef __attribute__((ext_vector_type(4))) float f32x4;

static __device__ __forceinline__ float lrelu(float x) { return x > 0.f ? x : NEG * x; }

static __device__ __forceinline__ float2 bfx2(unsigned u) {
    union { unsigned q; float f; } a, b;
    a.q = u << 16;
    b.q = u & 0xFFFF0000u;
    return make_float2(a.f, b.f);
}

static __device__ __forceinline__ unsigned packbf2(float x, float y) {
    unsigned xu = __float_as_uint(x), yu = __float_as_uint(y);
    xu = (xu + 0x7FFFu + ((xu >> 16) & 1u)) >> 16;
    yu = (yu + 0x7FFFu + ((yu >> 16) & 1u)) >> 16;
    return xu | (yu << 16);
}

static __device__ __forceinline__ unsigned short f2b(float x) {
    unsigned u = __float_as_uint(x);
    u = (u + 0x7FFFu + ((u >> 16) & 1u)) >> 16;
    return (unsigned short)u;
}

// ---------------- CSR build: deterministic multi-split, 4-byte records ----------------

__launch_bounds__(256)
__global__ void bhist_k(const int* __restrict__ dst, int* __restrict__ cnt) {
    __shared__ int hist[NB];
    int i = blockIdx.x, t = threadIdx.x;
    for (int b = t; b < NB; b += 256) hist[b] = 0;
    __syncthreads();
    int e0 = i * EPB;
    #pragma unroll
    for (int k = 0; k < EPB / 256; ++k) {
        int e = e0 + k * 256 + t;
        if (e < NE) atomicAdd(&hist[dst[e] >> BSHIFT], 1);
    }
    __syncthreads();
    for (int b = t; b < NB; b += 256) cnt[i * NB + b] = hist[b];
}

__launch_bounds__(256)
__global__ void bscan2_k(int* __restrict__ cnt, int* __restrict__ btot) {
    __shared__ int ps[256];
    int b = blockIdx.x, t = threadIdx.x;
    int i0 = 2 * t;
    int a = (i0 < NBLK) ? cnt[i0 * NB + b] : 0;
    int c = (i0 + 1 < NBLK) ? cnt[(i0 + 1) * NB + b] : 0;
    int s = a + c;
    ps[t] = s;
    __syncthreads();
    #pragma unroll
    for (int off = 1; off < 256; off <<= 1) {
        int x = (t >= off) ? ps[t - off] : 0;
        __syncthreads();
        ps[t] += x;
        __syncthreads();
    }
    int ex = ps[t] - s;
    if (i0 < NBLK) cnt[i0 * NB + b] = ex;
    if (i0 + 1 < NBLK) cnt[(i0 + 1) * NB + b] = ex + a;
    if (t == 255) btot[b] = ps[255];
}

__launch_bounds__(256)
__global__ void bscanB_k(const int* __restrict__ btot, int* __restrict__ bbase) {
    __shared__ int ps[256];
    int t = threadIdx.x;
    int j0 = 4 * t;
    int v[4]; int s = 0;
    #pragma unroll
    for (int k = 0; k < 4; ++k) { v[k] = (j0 + k < NB) ? btot[j0 + k] : 0; s += v[k]; }
    ps[t] = s;
    __syncthreads();
    #pragma unroll
    for (int off = 1; off < 256; off <<= 1) {
        int x = (t >= off) ? ps[t - off] : 0;
        __syncthreads();
        ps[t] += x;
        __syncthreads();
    }
    int run = ps[t] - s;
    #pragma unroll
    for (int k = 0; k < 4; ++k) { if (j0 + k < NB) bbase[j0 + k] = run; run += v[k]; }
    if (t == 0) bbase[NB] = NE;
}

// place 4-byte records: (d&127)<<17 | src   (src < 2^17)
__launch_bounds__(256)
__global__ void bplace_k(const int* __restrict__ src, const int* __restrict__ dst,
                         const int* __restrict__ cnt, const int* __restrict__ bbase,
                         unsigned* __restrict__ tmp) {
    __shared__ int loff[NB];
    int i = blockIdx.x, t = threadIdx.x;
    for (int b = t; b < NB; b += 256) loff[b] = bbase[b] + cnt[i * NB + b];
    __syncthreads();
    int e0 = i * EPB;
    #pragma unroll
    for (int k = 0; k < EPB / 256; ++k) {
        int e = e0 + k * 256 + t;
        if (e < NE) {
            int d = dst[e];
            int p = atomicAdd(&loff[d >> BSHIFT], 1);
            tmp[p] = ((unsigned)(d & 127) << 17) | (unsigned)src[e];
        }
    }
}

__launch_bounds__(256)
__global__ void scatter2_k(const unsigned* __restrict__ tmp, const int* __restrict__ bbase,
                           int* __restrict__ rowptr, int* __restrict__ col) {
    __shared__ int lcnt[BSZ];
    __shared__ int lrow[BSZ];
    __shared__ int ls[BSZ];
    int b = blockIdx.x, t = threadIdx.x;
    int n0 = b << BSHIFT;
    if (t < BSZ) lcnt[t] = 0;
    __syncthreads();
    int beg = bbase[b], end = bbase[b + 1];
    for (int p = beg + t; p < end; p += 256)
        atomicAdd(&lcnt[tmp[p] >> 17], 1);
    __syncthreads();
    if (t < BSZ) ls[t] = lcnt[t];
    __syncthreads();
    #pragma unroll
    for (int off = 1; off < BSZ; off <<= 1) {
        int x = 0;
        if (t < BSZ && t >= off) x = ls[t - off];
        __syncthreads();
        if (t < BSZ) ls[t] += x;
        __syncthreads();
    }
    if (t < BSZ) {
        int ex = ls[t] - lcnt[t];
        lrow[t] = beg + ex;
        if (n0 + t < NN) rowptr[n0 + t] = beg + ex;
        lcnt[t] = 0;
    }
    if (b == NB - 1 && t == 0) rowptr[NN] = NE;
    __syncthreads();
    for (int p = beg + t; p < end; p += 256) {
        unsigned v = tmp[p];
        int dloc = v >> 17;
        int s = (int)(v & 0x1FFFFu);
        int o = atomicAdd(&lcnt[dloc], 1);
        col[lrow[dloc] + o] = s;
    }
}

// ---------------- GEMM1 (MFMA): h1 = x @ W1 -> bf16, + fused ad1 epilogue ----------------

__launch_bounds__(256)
__global__ void gemm1_k(const float* __restrict__ x, const float* __restrict__ W,
                        const float* __restrict__ adst1,
                        unsigned short* __restrict__ h1b, float* __restrict__ ad1) {
    __shared__ unsigned short wsw[8 * 4 * 64 * 8];   // 16384 bf16 = 32 KB
    int tid = threadIdx.x;
    int wid = tid >> 6, lane = tid & 63;
    int r0 = blockIdx.x * 128 + wid * 32;

    #pragma unroll
    for (int it = 0; it < 16; ++it) {
        int idx4 = it * 256 + tid;
        int k = idx4 >> 4;
        int c0 = (idx4 & 15) * 4;
        float4 v = *(const float4*)&W[k * 64 + c0];
        int kt = k >> 5, kg = (k >> 3) & 3, kr = k & 7;
        float vv[4] = {v.x, v.y, v.z, v.w};
        #pragma unroll
        for (int j = 0; j < 4; ++j) {
            int c = c0 + j;
            int dest = (((kt * 4 + (c >> 4)) * 64) + kg * 16 + (c & 15)) * 8 + kr;
            wsw[dest] = f2b(vv[j]);
        }
    }
    __syncthreads();

    int arow0 = r0 + (lane & 15);
    int kg8 = (lane >> 4) * 8;
    f32x4 acc[2][4] = {};
    for (int kt = 0; kt < 8; ++kt) {
        short8 af[2];
        #pragma unroll
        for (int rt = 0; rt < 2; ++rt) {
            int row = arow0 + rt * 16;
            float4 v0 = make_float4(0.f, 0.f, 0.f, 0.f), v1 = v0;
            if (row < NN) {
                const float* px = &x[row * NF + kt * 32 + kg8];
                v0 = *(const float4*)px;
                v1 = *(const float4*)(px + 4);
            }
            unsigned p0 = packbf2(v0.x, v0.y), p1 = packbf2(v0.z, v0.w);
            unsigned p2 = packbf2(v1.x, v1.y), p3 = packbf2(v1.z, v1.w);
            af[rt][0] = (short)(p0 & 0xFFFF); af[rt][1] = (short)(p0 >> 16);
            af[rt][2] = (short)(p1 & 0xFFFF); af[rt][3] = (short)(p1 >> 16);
            af[rt][4] = (short)(p2 & 0xFFFF); af[rt][5] = (short)(p2 >> 16);
            af[rt][6] = (short)(p3 & 0xFFFF); af[rt][7] = (short)(p3 >> 16);
        }
        #pragma unroll
        for (int ct = 0; ct < 4; ++ct) {
            short8 bf = *(const short8*)&wsw[((kt * 4 + ct) * 64 + lane) * 8];
            acc[0][ct] = __builtin_amdgcn_mfma_f32_16x16x32_bf16(af[0], bf, acc[0][ct], 0, 0, 0);
            acc[1][ct] = __builtin_amdgcn_mfma_f32_16x16x32_bf16(af[1], bf, acc[1][ct], 0, 0, 0);
        }
    }

    int ccol = lane & 15;
    int crow0 = r0 + (lane >> 4) * 4;
    float adc[4];
    #pragma unroll
    for (int ct = 0; ct < 4; ++ct) adc[ct] = adst1[ct * 16 + ccol];
    int hbase = ccol >> 3;   // 0 or 1

    #pragma unroll
    for (int rt = 0; rt < 2; ++rt) {
        #pragma unroll
        for (int r = 0; r < 4; ++r) {
            int grow = crow0 + rt * 16 + r;
            if (grow < NN) {
                #pragma unroll
                for (int ct = 0; ct < 4; ++ct)
                    h1b[grow * D1 + ct * 16 + ccol] = f2b(acc[rt][ct][r]);
            }
            float pd[4];
            #pragma unroll
            for (int ct = 0; ct < 4; ++ct) pd[ct] = acc[rt][ct][r] * adc[ct];
            #pragma unroll
            for (int off = 1; off <= 4; off <<= 1)
                #pragma unroll
                for (int ct = 0; ct < 4; ++ct) pd[ct] += __shfl_xor(pd[ct], off, 64);
            if ((lane & 7) == 0 && grow < NN) {
                #pragma unroll
                for (int ct = 0; ct < 4; ++ct)
                    ad1[grow * 8 + ct * 2 + hbase] = pd[ct];
            }
        }
    }
}

// ---------------- w2vec precompute: [W2@asrc2 ; W2@adst2] (128 floats) ----------------

__launch_bounds__(128)
__global__ void w2pre_k(const float* __restrict__ W2, const float* __restrict__ asrc,
                        const float* __restrict__ adst, float* __restrict__ w2vec) {
    int t = threadIdx.x;
    int c = t & 63;
    const float* av = (t < 64) ? asrc : adst;
    float s = 0.f;
    #pragma unroll
    for (int j = 0; j < NC; ++j) s = fmaf(W2[c * NC + j], av[j], s);
    w2vec[t] = s;
}

// ---------------- aggregation layer 1: 2 nodes/wave, 4-edge groups ----------------
// half-wave (32 lanes) per node: 4 edge slots (g) x 8 channel lanes (ln).
// inline as1 recompute + fused attn2 epilogue. NN % 8 == 0 -> no partial blocks.

__launch_bounds__(256)
__global__ void agg1_k(const unsigned short* __restrict__ h1b, const float* __restrict__ asrc1,
                       const float* __restrict__ ad1,
                       const int* __restrict__ rowptr, const int* __restrict__ col,
                       const float* __restrict__ b1, const float* __restrict__ w2vec,
                       unsigned short* __restrict__ h1outb,
                       float* __restrict__ as2, float* __restrict__ ad2) {
    int tid = threadIdx.x;
    int lane = tid & 63;
    int half = lane >> 5;
    int n = blockIdx.x * 8 + (tid >> 6) * 2 + half;
    if (n >= NN) return;
    int l32 = lane & 31;
    int g = l32 >> 3, ln = l32 & 7;
    int row0 = rowptr[n];
    int d = rowptr[n + 1] - row0;
    float adh = ad1[n * 8 + ln];
    float a1c[8];
    #pragma unroll
    for (int k = 0; k < 8; ++k) a1c[k] = asrc1[ln * 8 + k];

    float acc[8] = {};
    float wsum = 0.f;
    for (int j = 0; j <= d; j += 4) {
        int jj = j + g;
        int s = (jj < d) ? col[row0 + jj] : n;   // virtual self-loop at jj==d
        uint4 hv = *(const uint4*)&h1b[s * D1 + ln * 8];
        float f[8];
        float2 p;
        p = bfx2(hv.x); f[0] = p.x; f[1] = p.y;
        p = bfx2(hv.y); f[2] = p.x; f[3] = p.y;
        p = bfx2(hv.z); f[4] = p.x; f[5] = p.y;
        p = bfx2(hv.w); f[6] = p.x; f[7] = p.y;
        float sa = 0.f;
        #pragma unroll
        for (int k = 0; k < 8; ++k) sa = fmaf(f[k], a1c[k], sa);   // as1 recomputed inline
        float wgt = (jj <= d) ? __expf(lrelu(sa + adh)) : 0.f;
        wsum += wgt;
        #pragma unroll
        for (int k = 0; k < 8; ++k) acc[k] = fmaf(f[k], wgt, acc[k]);
    }
    // reduce over the 4 edge groups (lane bits 3..4, within each 32-lane half)
    #pragma unroll
    for (int off = 8; off <= 16; off <<= 1) {
        wsum += __shfl_xor(wsum, off, 64);
        #pragma unroll
        for (int k = 0; k < 8; ++k) acc[k] += __shfl_xor(acc[k], off, 64);
    }
    if (g == 0) {
        float inv = 1.f / (wsum + 1e-16f);
        float vals[8];
        #pragma unroll
        for (int k = 0; k < 8; ++k) {
            float v = fmaf(acc[k], inv, b1[ln * 8 + k]);
            vals[k] = (v > 0.f) ? v : (__expf(v) - 1.f);   // ELU
        }
        unsigned u[4];
        #pragma unroll
        for (int k = 0; k < 4; ++k) u[k] = packbf2(vals[2 * k], vals[2 * k + 1]);
        uint4 w = {u[0], u[1], u[2], u[3]};
        *(uint4*)&h1outb[n * D1 + ln * 8] = w;
        // fused attn2: as2[n] = h1out[n].(W2@asrc2), ad2 likewise (reduce over ln bits 0..2)
        float pa = 0.f, pd = 0.f;
        #pragma unroll
        for (int k = 0; k < 8; ++k) {
            pa = fmaf(vals[k], w2vec[ln * 8 + k], pa);
            pd = fmaf(vals[k], w2vec[64 + ln * 8 + k], pd);
        }
        pa += __shfl_xor(pa, 1); pa += __shfl_xor(pa, 2); pa += __shfl_xor(pa, 4);
        pd += __shfl_xor(pd, 1); pd += __shfl_xor(pd, 2); pd += __shfl_xor(pd, 4);
        if (ln == 0) { as2[n] = pa; ad2[n] = pd; }
    }
}

// ---------------- aggregation layer 2: 2 nodes/wave, 4-edge groups -> zb ----------------

__launch_bounds__(256)
__global__ void agg2_k(const unsigned short* __restrict__ h1outb, const float* __restrict__ as2,
                       const float* __restrict__ ad2,
                       const int* __restrict__ rowptr, const int* __restrict__ col,
                       unsigned short* __restrict__ zb) {
    int tid = threadIdx.x;
    int lane = tid & 63;
    int half = lane >> 5;
    int n = blockIdx.x * 8 + (tid >> 6) * 2 + half;
    if (n >= NN) return;
    int l32 = lane & 31;
    int g = l32 >> 3, ln = l32 & 7;
    int row0 = rowptr[n];
    int d = rowptr[n + 1] - row0;
    float adn = ad2[n];

    float acc[8] = {};
    float wsum = 0.f;
    for (int j = 0; j <= d; j += 4) {
        int jj = j + g;
        int s = (jj < d) ? col[row0 + jj] : n;
        float e = lrelu(as2[s] + adn);
        float wgt = (jj <= d) ? __expf(e) : 0.f;
        wsum += wgt;
        uint4 hv = *(const uint4*)&h1outb[s * D1 + ln * 8];
        float2 p;
        p = bfx2(hv.x); acc[0] = fmaf(p.x, wgt, acc[0]); acc[1] = fmaf(p.y, wgt, acc[1]);
        p = bfx2(hv.y); acc[2] = fmaf(p.x, wgt, acc[2]); acc[3] = fmaf(p.y, wgt, acc[3]);
        p = bfx2(hv.z); acc[4] = fmaf(p.x, wgt, acc[4]); acc[5] = fmaf(p.y, wgt, acc[5]);
        p = bfx2(hv.w); acc[6] = fmaf(p.x, wgt, acc[6]); acc[7] = fmaf(p.y, wgt, acc[7]);
    }
    #pragma unroll
    for (int off = 8; off <= 16; off <<= 1) {
        wsum += __shfl_xor(wsum, off, 64);
        #pragma unroll
        for (int k = 0; k < 8; ++k) acc[k] += __shfl_xor(acc[k], off, 64);
    }
    if (g == 0) {
        float inv = 1.f / (wsum + 1e-16f);
        unsigned u[4];
        #pragma unroll
        for (int k = 0; k < 4; ++k)
            u[k] = packbf2(acc[2 * k] * inv, acc[2 * k + 1] * inv);
        uint4 w = {u[0], u[1], u[2], u[3]};
        *(uint4*)&zb[n * D1 + ln * 8] = w;
    }
}

// ---------------- GEMM2: out = z @ W2 + b2   [100000,64]x[64,40] -> d_out ----------------

__launch_bounds__(256)
__global__ void gemm2_k(const unsigned short* __restrict__ zb, const float* __restrict__ W2,
                        const float* __restrict__ b2, float* __restrict__ out) {
    __shared__ float xs[64 * 68];
    __shared__ float wsm[64 * 40];
    __shared__ float bs[40];
    int r0 = blockIdx.x * 64;
    int tid = threadIdx.x;
    #pragma unroll
    for (int it = 0; it < 4; ++it) {
        int idx = tid + it * 256;       // 0..1023
        int row = idx >> 4;             // 0..63
        int q = (idx & 15) * 4;         // col quad base
        int gr = r0 + row;
        float f0 = 0.f, f1 = 0.f, f2 = 0.f, f3 = 0.f;
        if (gr < NN) {
            uint2 v = *(const uint2*)&zb[gr * D1 + q];
            float2 p0 = bfx2(v.x), p1 = bfx2(v.y);
            f0 = p0.x; f1 = p0.y; f2 = p1.x; f3 = p1.y;
        }
        xs[row * 68 + q] = f0;
        xs[row * 68 + q + 1] = f1;
        xs[row * 68 + q + 2] = f2;
        xs[row * 68 + q + 3] = f3;
    }
    #pragma unroll
    for (int it = 0; it < 10; ++it) {
        int idx = tid + it * 256;
        if (idx < 64 * 40) wsm[idx] = W2[idx];
    }
    if (tid < 40) bs[tid] = b2[tid];
    __syncthreads();
    int r = tid >> 2, q = tid & 3;
    float acc[10] = {};
    #pragma unroll 4
    for (int k = 0; k < 64; ++k) {
        float xv = xs[r * 68 + k];
        #pragma unroll
        for (int i = 0; i < 10; ++i)
            acc[i] = fmaf(xv, wsm[k * 40 + q * 10 + i], acc[i]);
    }
    int gr = r0 + r;
    if (gr < NN) {
        #pragma unroll
        for (int i = 0; i < 10; ++i) out[gr * NC + q * 10 + i] = acc[i] + bs[q * 10 + i];
    }
}

// ---------------- launcher ----------------

extern "C" void kernel_launch(void* const* d_in, const int* in_sizes, int n_in,
                              void* d_out, int out_size, void* d_ws, size_t ws_size,
                              hipStream_t stream) {
    const float* x = (const float*)d_in[0];
    const int* ei = (const int*)d_in[1];   // harness passes integer inputs as int32
    const int* src = ei;
    const int* dst = ei + NE;
    const float* W1 = (const float*)d_in[2];
    const float* asrc1 = (const float*)d_in[3];
    const float* adst1 = (const float*)d_in[4];
    const float* b1 = (const float*)d_in[5];
    const float* W2 = (const float*)d_in[6];
    const float* asrc2 = (const float*)d_in[7];
    const float* adst2 = (const float*)d_in[8];
    const float* b2 = (const float*)d_in[9];
    float* out = (float*)d_out;

    // workspace layout (total 46,006,912 B):
    //   [0,12800000)          h1b bf16 [N][64]; zb bf16 [N][64] aliases (h1b dead after agg1)
    //   [16000000,19200000)   ad1 fp32 [N][8]
    //   [25600000,38400000)   h1outb bf16 [N][64]; tmp u32 [NE] aliases (dead before agg1)
    //   [38400000,38800000)   as2 fp32 [N]
    //   [38800000,39200000)   ad2 fp32 [N]
    //   [39200000,45600000)   col int [NE]; cnt int [NBLK*NB] aliases (dead before scatter2)
    //   [45600000,46000128)   rowptr int [N+1, padded]
    //   [46000128,46003260)   btot int [NB]
    //   [46003264,46006400)   bbase int [NB+1, padded]
    //   [46006400,46006912)   w2vec fp32 [128]
    char* ws = (char*)d_ws;
    unsigned short* h1b    = (unsigned short*)(ws + 0);
    unsigned short* zb     = (unsigned short*)(ws + 0);      // alias: h1b dead after agg1
    float*          ad1    = (float*)(ws + 16000000);
    unsigned short* h1outb = (unsigned short*)(ws + 25600000);
    unsigned*       tmp    = (unsigned*)(ws + 25600000);     // alias: dead before agg1 writes h1outb
    float*          as2    = (float*)(ws + 38400000);
    float*          ad2    = (float*)(ws + 38800000);
    int*            col    = (int*)(ws + 39200000);
    int*            cnt    = (int*)(ws + 39200000);          // alias: dead before scatter2 writes col
    int*            rowptr = (int*)(ws + 45600000);
    int*            btot   = (int*)(ws + 46000128);
    int*            bbase  = (int*)(ws + 46003264);
    float*          w2vec  = (float*)(ws + 46006400);

    bhist_k<<<NBLK, 256, 0, stream>>>(dst, cnt);
    bscan2_k<<<NB, 256, 0, stream>>>(cnt, btot);
    bscanB_k<<<1, 256, 0, stream>>>(btot, bbase);
    bplace_k<<<NBLK, 256, 0, stream>>>(src, dst, cnt, bbase, tmp);
    scatter2_k<<<NB, 256, 0, stream>>>(tmp, bbase, rowptr, col);

    gemm1_k<<<(NN + 127) / 128, 256, 0, stream>>>(x, W1, adst1, h1b, ad1);
    w2pre_k<<<1, 128, 0, stream>>>(W2, asrc2, adst2, w2vec);
    agg1_k<<<(NN + 7) / 8, 256, 0, stream>>>(h1b, asrc1, ad1, rowptr, col, b1, w2vec,
                                             h1outb, as2, ad2);

    agg2_k<<<(NN + 7) / 8, 256, 0, stream>>>(h1outb, as2, ad2, rowptr, col, zb);
    gemm2_k<<<(NN + 63) / 64, 256, 0, stream>>>(zb, W2, b2, out);
}